// Round 2
// baseline (55988.019 us; speedup 1.0000x reference)
//
#include <hip/hip_runtime.h>
#include <math.h>

#define T_STEPS 8192
#define HID 2048
#define H3 6144
#define NBLK 256
#define CHUNK 2048

typedef float f32x4 __attribute__((ext_vector_type(4)));
typedef float f32x2 __attribute__((ext_vector_type(2)));

// ---------------------------------------------------------------------------
// Coherent (cross-XCD) access: sc0 sc1 bypasses L1/L2 to the Infinity-Cache
// coherence point. Validated (R3/R4) for producer/consumer h exchange.
// ---------------------------------------------------------------------------
__device__ __forceinline__ float cload_f1(const float* p) {
    float r;
    asm volatile("global_load_dword %0, %1, off sc0 sc1\n\t"
                 "s_waitcnt vmcnt(0)"
                 : "=&v"(r) : "v"(p) : "memory");
    return r;
}
__device__ __forceinline__ float2 cload_f2(const float* p) {
    float2 r;
    asm volatile("global_load_dwordx2 %0, %1, off sc0 sc1\n\t"
                 "s_waitcnt vmcnt(0)"
                 : "=&v"(r) : "v"(p) : "memory");
    return r;
}
__device__ __forceinline__ void cstore_f1(float* p, float x) {
    asm volatile("global_store_dword %0, %1, off sc0 sc1"
                 :: "v"(p), "v"(x) : "memory");
}

// ---------------------------------------------------------------------------
// Fast gates: v_exp_f32 (2^x) based sigmoid/tanh. libm expf/tanhf are branchy
// (~300-600 cy) and sit on the serial producer path; these are ~30 cy.
// Saturation is exact: exp2(+inf)->inf->rcp->0; exp2(-inf)->0.
// ---------------------------------------------------------------------------
#if __has_builtin(__builtin_amdgcn_exp2f)
__device__ __forceinline__ float fexp2(float x) { return __builtin_amdgcn_exp2f(x); }
#else
__device__ __forceinline__ float fexp2(float x) {
    float r; asm("v_exp_f32 %0, %1" : "=v"(r) : "v"(x)); return r;
}
#endif
__device__ __forceinline__ float frcp(float x) { return __builtin_amdgcn_rcpf(x); }
__device__ __forceinline__ float fsigmoid(float x) {
    return frcp(1.f + fexp2(-1.44269504089f * x));
}
__device__ __forceinline__ float ftanh_(float x) {
    return 2.f * frcp(1.f + fexp2(-2.88539008178f * x)) - 1.f;
}

// ---------------------------------------------------------------------------
// fp32 GEMM: C[M,N] = A[M,K] @ B[N,K]^T + bias, optional ReLU.
// ---------------------------------------------------------------------------
template<int RELU>
__global__ __launch_bounds__(256) void sgemm_bias(
    const float* __restrict__ A, const float* __restrict__ B,
    const float* __restrict__ bias, float* __restrict__ C,
    int M, int N, int K)
{
    __shared__ float As[16][64];
    __shared__ float Bs[16][64];
    const int tid = threadIdx.x;
    const int tm = tid & 15;
    const int tn = tid >> 4;
    const int m0 = blockIdx.y * 64;
    const int n0 = blockIdx.x * 64;
    const int lm = tid >> 2;
    const int lk = (tid & 3) * 4;

    float c[4][4] = {};

    for (int k0 = 0; k0 < K; k0 += 16) {
        float4 av = *(const float4*)(A + (size_t)(m0 + lm) * K + k0 + lk);
        float4 bv = make_float4(0.f, 0.f, 0.f, 0.f);
        const int bn = n0 + lm;
        if (bn < N) bv = *(const float4*)(B + (size_t)bn * K + k0 + lk);
        __syncthreads();
        As[lk+0][lm] = av.x; As[lk+1][lm] = av.y; As[lk+2][lm] = av.z; As[lk+3][lm] = av.w;
        Bs[lk+0][lm] = bv.x; Bs[lk+1][lm] = bv.y; Bs[lk+2][lm] = bv.z; Bs[lk+3][lm] = bv.w;
        __syncthreads();
        #pragma unroll
        for (int kk = 0; kk < 16; kk++) {
            float4 a4 = *(const float4*)&As[kk][tm * 4];
            float4 b4 = *(const float4*)&Bs[kk][tn * 4];
            c[0][0] += a4.x * b4.x; c[0][1] += a4.x * b4.y; c[0][2] += a4.x * b4.z; c[0][3] += a4.x * b4.w;
            c[1][0] += a4.y * b4.x; c[1][1] += a4.y * b4.y; c[1][2] += a4.y * b4.z; c[1][3] += a4.y * b4.w;
            c[2][0] += a4.z * b4.x; c[2][1] += a4.z * b4.y; c[2][2] += a4.z * b4.z; c[2][3] += a4.z * b4.w;
            c[3][0] += a4.w * b4.x; c[3][1] += a4.w * b4.y; c[3][2] += a4.w * b4.z; c[3][3] += a4.w * b4.w;
        }
    }

    const int mrow = m0 + tm * 4;
    #pragma unroll
    for (int i = 0; i < 4; i++) {
        #pragma unroll
        for (int j = 0; j < 4; j++) {
            const int n = n0 + tn * 4 + j;
            if (n < N) {
                float v = c[i][j] + bias[n];
                if (RELU) v = fmaxf(v, 0.f);
                C[(size_t)(mrow + i) * N + n] = v;
            }
        }
    }
}

// ---------------------------------------------------------------------------
// fp32 GEMM (B not transposed): C[M,N] = A[M,K] @ B[K,N]. No bias.
// Used once: W_comb[6144,64] = w_ih[6144,2048] @ enc_w[2048,64].
// ---------------------------------------------------------------------------
__global__ __launch_bounds__(256) void sgemm_nn(
    const float* __restrict__ A, const float* __restrict__ B,
    float* __restrict__ C, int M, int N, int K)
{
    __shared__ float As[16][64];
    __shared__ float Bs[16][64];
    const int tid = threadIdx.x;
    const int tm = tid & 15;
    const int tn = tid >> 4;
    const int m0 = blockIdx.y * 64;
    const int n0 = blockIdx.x * 64;
    const int lm = tid >> 2;
    const int lk = (tid & 3) * 4;
    const int bk  = tid >> 4;
    const int bn4 = (tid & 15) * 4;

    float c[4][4] = {};

    for (int k0 = 0; k0 < K; k0 += 16) {
        float4 av = *(const float4*)(A + (size_t)(m0 + lm) * K + k0 + lk);
        float4 bv = *(const float4*)(B + (size_t)(k0 + bk) * N + n0 + bn4);
        __syncthreads();
        As[lk+0][lm] = av.x; As[lk+1][lm] = av.y; As[lk+2][lm] = av.z; As[lk+3][lm] = av.w;
        *(float4*)&Bs[bk][bn4] = bv;
        __syncthreads();
        #pragma unroll
        for (int kk = 0; kk < 16; kk++) {
            float4 a4 = *(const float4*)&As[kk][tm * 4];
            float4 b4 = *(const float4*)&Bs[kk][tn * 4];
            c[0][0] += a4.x * b4.x; c[0][1] += a4.x * b4.y; c[0][2] += a4.x * b4.z; c[0][3] += a4.x * b4.w;
            c[1][0] += a4.y * b4.x; c[1][1] += a4.y * b4.y; c[1][2] += a4.y * b4.z; c[1][3] += a4.y * b4.w;
            c[2][0] += a4.z * b4.x; c[2][1] += a4.z * b4.y; c[2][2] += a4.z * b4.z; c[2][3] += a4.z * b4.w;
            c[3][0] += a4.w * b4.x; c[3][1] += a4.w * b4.y; c[3][2] += a4.w * b4.z; c[3][3] += a4.w * b4.w;
        }
    }

    const int mrow = m0 + tm * 4;
    #pragma unroll
    for (int i = 0; i < 4; i++) {
        #pragma unroll
        for (int j = 0; j < 4; j++)
            C[(size_t)(mrow + i) * N + n0 + tn * 4 + j] = c[i][j];
    }
}

// ---------------------------------------------------------------------------
// b_comb[r] = dot(w_ih[r,:], enc_b) + b_ih[r].  One wave per row.
// ---------------------------------------------------------------------------
__global__ __launch_bounds__(256) void bcomb_kernel(
    const float* __restrict__ w_ih, const float* __restrict__ enc_b,
    const float* __restrict__ b_ih, float* __restrict__ b_comb)
{
    const int wv = threadIdx.x >> 6, lane = threadIdx.x & 63;
    const int r = blockIdx.x * 4 + wv;
    const float* row = w_ih + (size_t)r * HID;
    float acc = 0.f;
    for (int j = lane; j < HID; j += 64) acc += row[j] * enc_b[j];
    #pragma unroll
    for (int m = 32; m >= 1; m >>= 1) acc += __shfl_xor(acc, m, 64);
    if (lane == 0) b_comb[r] = acc + b_ih[r];
}

// ---------------------------------------------------------------------------
// Persistent GRU scan. 256 blocks x 1024 threads, 1 block/CU.
// R4 structure (central wave-0 gates, early spin, no end barrier) with a
// flag/data SPLIT exchange:
//  * R4's fused 16B atoms made every poll round refetch 4 MB chip-wide
//    (1024 thr x 16B x 256 blk) -> ~1200cy of IC BW-time per round, 2-3
//    rounds/step. R5 proved the fix is NOT a barrier (serializing publish
//    before poll-issue cost +60%); the fix is cheaper rounds.
//  * Producer block b: 8 lanes store h (4B each, contiguous 32B, sc0sc1),
//    s_waitcnt vmcnt(0) to drain to the coherence point, then ONE 4B flag
//    store flags[phase][b] = base+t+1. Flag fresh => data fresh.
//  * Consumer thread tid needs h[2tid],h[2tid+1], both from block tid/4:
//    spins on flags[phase][tid/4] (a wave covers 16 flags = one 64B line;
//    round = 1KB/block = 0.25MB chip-wide, 16x less), then ONE 8B dwordx2
//    data load (2MB chip-wide, once per step instead of every round).
//  * Overwrite race: block p publishes t+2 only after consuming t+1, which
//    requires all blocks published t+1, which requires all consumed t
//    (block-wide __syncthreads after the data read). Same proof as R4.
// ---------------------------------------------------------------------------
__global__ __launch_bounds__(1024, 4) void gru_scan(
    const float* __restrict__ w_hh, const float* __restrict__ b_n,
    const float* __restrict__ ig,   // [steps,3,H] fp32 for this chunk
    float* __restrict__ hs,         // [steps,H] output states (chunk base)
    float* __restrict__ h_pub,      // 2 x 2048 published h, zeroed at launch
    float* __restrict__ flags,      // 2 x 256 per-block stamps, zeroed
    int base, int steps)
{
    __shared__ float h_lds[HID];
    __shared__ float pg[16][3];
    __shared__ float hg_lds[24];
    const int tid  = threadIdx.x;
    const int lane = tid & 63;
    const int w    = tid >> 6;      // wave 0..15
    const int pr   = tid & 127;     // pair-local lane 0..127
    const int k    = tid >> 7;      // wave-pair 0..7
    const int b    = blockIdx.x;

    // ---- 48 weights per thread (12 float4), coalesced ----
    // rows idx3 = 3k+j ; cols 4*pr + 512*m (m=0..3)
    float4 wreg[3][4];
    #pragma unroll
    for (int j = 0; j < 3; j++) {
        const int idx3 = 3 * k + j;
        const float* wp = w_hh +
            (size_t)((idx3 >> 3) * HID + b * 8 + (idx3 & 7)) * HID;
        #pragma unroll
        for (int m = 0; m < 4; m++)
            wreg[j][m] = *(const float4*)(wp + 4 * pr + 512 * m);
    }

    const int i = b * 8 + tid;                 // valid for tid<8
    const float bn = (tid < 8) ? b_n[i] : 0.f;

    for (int t = 0; t < steps; t++) {
        // ig loads for this step (tid<8, wave 0) - in flight during poll
        float ig0 = 0.f, ig1 = 0.f, ig2 = 0.f;
        if (tid < 8) {
            const float* p = ig + (size_t)t * H3 + i;
            ig0 = p[0]; ig1 = p[HID]; ig2 = p[2 * HID];
        }

        // ---- spin on own producer's 4B flag (cheap rounds), then fetch 8B ----
        const float target = (float)(base + t);          // exact in fp32
        const int ph = t & 1;
        const float* fp = flags + ph * 256 + (tid >> 2);
        float f;
        do { f = cload_f1(fp); } while (f < target);
        float2 hv = cload_f2(h_pub + ph * 2048 + 2 * tid);
        *(float2*)&h_lds[2 * tid] = hv;
        __syncthreads();

        // ---- dot: rows 3k..3k+2, cols 4*pr+512m, weights in registers ----
        float a0 = 0.f, a1 = 0.f, a2 = 0.f;
        #pragma unroll
        for (int m = 0; m < 4; m++) {
            float4 h4 = *(const float4*)&h_lds[4 * pr + 512 * m];
            a0 += wreg[0][m].x * h4.x + wreg[0][m].y * h4.y + wreg[0][m].z * h4.z + wreg[0][m].w * h4.w;
            a1 += wreg[1][m].x * h4.x + wreg[1][m].y * h4.y + wreg[1][m].z * h4.z + wreg[1][m].w * h4.w;
            a2 += wreg[2][m].x * h4.x + wreg[2][m].y * h4.y + wreg[2][m].z * h4.z + wreg[2][m].w * h4.w;
        }
        #pragma unroll
        for (int s = 32; s >= 1; s >>= 1) {
            a0 += __shfl_xor(a0, s, 64);
            a1 += __shfl_xor(a1, s, 64);
            a2 += __shfl_xor(a2, s, 64);
        }
        if (lane == 0) { pg[w][0] = a0; pg[w][1] = a1; pg[w][2] = a2; }
        __syncthreads();

        // ---- combine + gates + publish (all in wave 0, lockstep) ----
        if (w == 0) {
            if (lane < 24) {
                const int kk = lane / 3, j = lane - 3 * kk;
                hg_lds[lane] = pg[2 * kk][j] + pg[2 * kk + 1][j];
            }
            asm volatile("s_waitcnt lgkmcnt(0)" ::: "memory");  // intra-wave LDS wr->rd
            float h_new = 0.f;
            if (lane < 8) {
                const float r = fsigmoid(ig0 + hg_lds[lane]);
                const float z = fsigmoid(ig1 + hg_lds[8 + lane]);
                const float n = ftanh_(ig2 + r * (hg_lds[16 + lane] + bn));
                const float hp = h_lds[i];
                h_new = n + z * (hp - n);
                cstore_f1(h_pub + ((t + 1) & 1) * 2048 + i, h_new);
            }
            // drain data stores to the coherence point, THEN publish flag
            asm volatile("s_waitcnt vmcnt(0)" ::: "memory");
            if (lane == 0)
                cstore_f1(flags + ((t + 1) & 1) * 256 + b, target + 1.f);
            if (lane < 8)
                hs[(size_t)t * HID + i] = h_new;   // cached store, off critical path
        }
        // no end barrier: early spin on the cheap flag preserves overlap
    }
}

// ---------------------------------------------------------------------------
extern "C" void kernel_launch(void* const* d_in, const int* in_sizes, int n_in,
                              void* d_out, int out_size, void* d_ws, size_t ws_size,
                              hipStream_t stream) {
    const float* x     = (const float*)d_in[0];
    const float* enc_w = (const float*)d_in[1];
    const float* enc_b = (const float*)d_in[2];
    const float* w_ih  = (const float*)d_in[3];
    const float* w_hh  = (const float*)d_in[4];
    const float* b_ih  = (const float*)d_in[5];
    const float* b_n   = (const float*)d_in[6];
    const float* w0    = (const float*)d_in[7];
    const float* b0    = (const float*)d_in[8];
    const float* w1    = (const float*)d_in[9];
    const float* b1    = (const float*)d_in[10];
    const float* w2    = (const float*)d_in[11];
    const float* b2    = (const float*)d_in[12];
    float* out = (float*)d_out;

    // workspace (~136 MB): R1 64MB (ig chunk -> dec h1), R2 64MB (hs -> dec h2)
    float* R1    = (float*)d_ws;                          // 16,777,216 f
    float* R2    = R1 + (size_t)16777216;                 // 16,777,216 f
    float* wcomb = R2 + (size_t)16777216;                 // 393,216 f
    float* bcomb = wcomb + 393216;                        // 6,144 f
    float* h_pub = bcomb + 6144;                          // 2*2048 f
    float* flags = h_pub + 2 * 2048;                      // 2*256 f

    (void)hipMemsetAsync(h_pub, 0, (2 * 2048 + 2 * 256) * sizeof(float), stream);

    // fold encoder into GRU input weights:
    //   W_comb = w_ih @ enc_w   [6144,64];  b_comb = w_ih @ enc_b + b_ih
    sgemm_nn<<<dim3(1, 96), 256, 0, stream>>>(w_ih, enc_w, wcomb, 6144, 64, 2048);
    bcomb_kernel<<<dim3(1536), 256, 0, stream>>>(w_ih, enc_b, b_ih, bcomb);

    // chunked: ig = x @ W_comb^T + b_comb (K=64), then sequential scan
    for (int c = 0; c < T_STEPS / CHUNK; c++) {
        sgemm_bias<0><<<dim3(H3 / 64, CHUNK / 64), 256, 0, stream>>>(
            x + (size_t)c * CHUNK * 64, wcomb, bcomb, R1, CHUNK, H3, 64);
        gru_scan<<<dim3(NBLK), dim3(1024), 0, stream>>>(
            w_hh, b_n, R1, R2 + (size_t)c * CHUNK * HID, h_pub, flags,
            c * CHUNK, CHUNK);
    }

    // decoder MLP (aliased: R2=hs -> R1=h1 -> R2=h2 -> out)
    sgemm_bias<1><<<dim3(HID / 64, T_STEPS / 64), 256, 0, stream>>>(
        R2, w0, b0, R1, T_STEPS, HID, HID);
    sgemm_bias<1><<<dim3(HID / 64, T_STEPS / 64), 256, 0, stream>>>(
        R1, w1, b1, R2, T_STEPS, HID, HID);
    sgemm_bias<0><<<dim3(1, T_STEPS / 64), 256, 0, stream>>>(
        R2, w2, b2, out, T_STEPS, 49, 2048);
}

// Round 3
// 25832.904 us; speedup vs baseline: 2.1673x; 2.1673x over previous
//
#include <hip/hip_runtime.h>
#include <math.h>

#define T_STEPS 8192
#define HID 2048
#define H3 6144
#define NBLK 256
#define CHUNK 2048

typedef float f32x4 __attribute__((ext_vector_type(4)));

// ---------------------------------------------------------------------------
// Coherent (cross-XCD) access: sc0 sc1 bypasses L1/L2 to the Infinity-Cache
// coherence point. Validated (R3/R4) for producer/consumer h exchange.
// R5/R6 falsified both "improvements": end-barrier (+60%) and centralized
// flags (+580%, IC hot-line serialization). Distributed 16B fused atoms +
// early spin is the proven optimum; do not touch the exchange protocol.
// ---------------------------------------------------------------------------
__device__ __forceinline__ float4 cload_f4(const float* p) {
    float4 r;
    asm volatile("global_load_dwordx4 %0, %1, off sc0 sc1\n\t"
                 "s_waitcnt vmcnt(0)"
                 : "=&v"(r) : "v"(p) : "memory");
    return r;
}
__device__ __forceinline__ void cstore_f4(float4* p, float x, float y,
                                          float z, float w) {
    f32x4 v; v[0] = x; v[1] = y; v[2] = z; v[3] = w;
    asm volatile("global_store_dwordx4 %0, %1, off sc0 sc1"
                 :: "v"(p), "v"(v) : "memory");
}

// LDS-only barrier: __syncthreads() drains vmcnt too, which serializes
// outstanding ig-load / hs-store acks into the barrier. These barriers only
// order LDS traffic -> drain lgkmcnt only, leave vmem in flight.
#define BAR_LDS() asm volatile("s_waitcnt lgkmcnt(0)\n\ts_barrier" ::: "memory")

// ---------------------------------------------------------------------------
// Fast gates: v_exp_f32 (2^x) based sigmoid/tanh. libm expf/tanhf are branchy
// (~300-500 cy) and sit on the serial wave-0 publish path; these are ~30 cy.
// Saturation: exp2(-inf)->0 (sig->1), exp2(+inf)->inf->rcp->0 (sig->0).
// ---------------------------------------------------------------------------
__device__ __forceinline__ float fexp2(float x) {
    return __builtin_amdgcn_exp2f(x);
}
__device__ __forceinline__ float frcp(float x) { return __builtin_amdgcn_rcpf(x); }
__device__ __forceinline__ float fsigmoid(float x) {
    return frcp(1.f + fexp2(-1.44269504089f * x));
}
__device__ __forceinline__ float ftanh_(float x) {
    return 2.f * frcp(1.f + fexp2(-2.88539008178f * x)) - 1.f;
}

// ---------------------------------------------------------------------------
// fp32 GEMM: C[M,N] = A[M,K] @ B[N,K]^T + bias, optional ReLU.
// ---------------------------------------------------------------------------
template<int RELU>
__global__ __launch_bounds__(256) void sgemm_bias(
    const float* __restrict__ A, const float* __restrict__ B,
    const float* __restrict__ bias, float* __restrict__ C,
    int M, int N, int K)
{
    __shared__ float As[16][64];
    __shared__ float Bs[16][64];
    const int tid = threadIdx.x;
    const int tm = tid & 15;
    const int tn = tid >> 4;
    const int m0 = blockIdx.y * 64;
    const int n0 = blockIdx.x * 64;
    const int lm = tid >> 2;
    const int lk = (tid & 3) * 4;

    float c[4][4] = {};

    for (int k0 = 0; k0 < K; k0 += 16) {
        float4 av = *(const float4*)(A + (size_t)(m0 + lm) * K + k0 + lk);
        float4 bv = make_float4(0.f, 0.f, 0.f, 0.f);
        const int bn = n0 + lm;
        if (bn < N) bv = *(const float4*)(B + (size_t)bn * K + k0 + lk);
        __syncthreads();
        As[lk+0][lm] = av.x; As[lk+1][lm] = av.y; As[lk+2][lm] = av.z; As[lk+3][lm] = av.w;
        Bs[lk+0][lm] = bv.x; Bs[lk+1][lm] = bv.y; Bs[lk+2][lm] = bv.z; Bs[lk+3][lm] = bv.w;
        __syncthreads();
        #pragma unroll
        for (int kk = 0; kk < 16; kk++) {
            float4 a4 = *(const float4*)&As[kk][tm * 4];
            float4 b4 = *(const float4*)&Bs[kk][tn * 4];
            c[0][0] += a4.x * b4.x; c[0][1] += a4.x * b4.y; c[0][2] += a4.x * b4.z; c[0][3] += a4.x * b4.w;
            c[1][0] += a4.y * b4.x; c[1][1] += a4.y * b4.y; c[1][2] += a4.y * b4.z; c[1][3] += a4.y * b4.w;
            c[2][0] += a4.z * b4.x; c[2][1] += a4.z * b4.y; c[2][2] += a4.z * b4.z; c[2][3] += a4.z * b4.w;
            c[3][0] += a4.w * b4.x; c[3][1] += a4.w * b4.y; c[3][2] += a4.w * b4.z; c[3][3] += a4.w * b4.w;
        }
    }

    const int mrow = m0 + tm * 4;
    #pragma unroll
    for (int i = 0; i < 4; i++) {
        #pragma unroll
        for (int j = 0; j < 4; j++) {
            const int n = n0 + tn * 4 + j;
            if (n < N) {
                float v = c[i][j] + bias[n];
                if (RELU) v = fmaxf(v, 0.f);
                C[(size_t)(mrow + i) * N + n] = v;
            }
        }
    }
}

// ---------------------------------------------------------------------------
// fp32 GEMM (B not transposed): C[M,N] = A[M,K] @ B[K,N]. No bias.
// Used once: W_comb[6144,64] = w_ih[6144,2048] @ enc_w[2048,64].
// ---------------------------------------------------------------------------
__global__ __launch_bounds__(256) void sgemm_nn(
    const float* __restrict__ A, const float* __restrict__ B,
    float* __restrict__ C, int M, int N, int K)
{
    __shared__ float As[16][64];
    __shared__ float Bs[16][64];
    const int tid = threadIdx.x;
    const int tm = tid & 15;
    const int tn = tid >> 4;
    const int m0 = blockIdx.y * 64;
    const int n0 = blockIdx.x * 64;
    const int lm = tid >> 2;
    const int lk = (tid & 3) * 4;
    const int bk  = tid >> 4;
    const int bn4 = (tid & 15) * 4;

    float c[4][4] = {};

    for (int k0 = 0; k0 < K; k0 += 16) {
        float4 av = *(const float4*)(A + (size_t)(m0 + lm) * K + k0 + lk);
        float4 bv = *(const float4*)(B + (size_t)(k0 + bk) * N + n0 + bn4);
        __syncthreads();
        As[lk+0][lm] = av.x; As[lk+1][lm] = av.y; As[lk+2][lm] = av.z; As[lk+3][lm] = av.w;
        *(float4*)&Bs[bk][bn4] = bv;
        __syncthreads();
        #pragma unroll
        for (int kk = 0; kk < 16; kk++) {
            float4 a4 = *(const float4*)&As[kk][tm * 4];
            float4 b4 = *(const float4*)&Bs[kk][tn * 4];
            c[0][0] += a4.x * b4.x; c[0][1] += a4.x * b4.y; c[0][2] += a4.x * b4.z; c[0][3] += a4.x * b4.w;
            c[1][0] += a4.y * b4.x; c[1][1] += a4.y * b4.y; c[1][2] += a4.y * b4.z; c[1][3] += a4.y * b4.w;
            c[2][0] += a4.z * b4.x; c[2][1] += a4.z * b4.y; c[2][2] += a4.z * b4.z; c[2][3] += a4.z * b4.w;
            c[3][0] += a4.w * b4.x; c[3][1] += a4.w * b4.y; c[3][2] += a4.w * b4.z; c[3][3] += a4.w * b4.w;
        }
    }

    const int mrow = m0 + tm * 4;
    #pragma unroll
    for (int i = 0; i < 4; i++) {
        #pragma unroll
        for (int j = 0; j < 4; j++)
            C[(size_t)(mrow + i) * N + n0 + tn * 4 + j] = c[i][j];
    }
}

// ---------------------------------------------------------------------------
// b_comb[r] = dot(w_ih[r,:], enc_b) + b_ih[r].  One wave per row.
// ---------------------------------------------------------------------------
__global__ __launch_bounds__(256) void bcomb_kernel(
    const float* __restrict__ w_ih, const float* __restrict__ enc_b,
    const float* __restrict__ b_ih, float* __restrict__ b_comb)
{
    const int wv = threadIdx.x >> 6, lane = threadIdx.x & 63;
    const int r = blockIdx.x * 4 + wv;
    const float* row = w_ih + (size_t)r * HID;
    float acc = 0.f;
    for (int j = lane; j < HID; j += 64) acc += row[j] * enc_b[j];
    #pragma unroll
    for (int m = 32; m >= 1; m >>= 1) acc += __shfl_xor(acc, m, 64);
    if (lane == 0) b_comb[r] = acc + b_ih[r];
}

// ---------------------------------------------------------------------------
// Persistent GRU scan. 256 blocks x 1024 threads, 1 block/CU.
// R4 structure EXACTLY (proven 6.3 ms/dispatch): fused h+stamp 16B atoms,
// per-thread distributed poll addresses, early spin, no end barrier,
// self-atom gating for intra-block LDS reuse ordering.
// R7 tail-only edits (publish-side critical path):
//   * fast v_exp-based gates instead of libm expf/tanhf
//   * lgkm-only barriers (no vmcnt drain at barriers)
//   * hs cached store moved after the atom publish
// ---------------------------------------------------------------------------
__global__ __launch_bounds__(1024, 4) void gru_scan(
    const float* __restrict__ w_hh, const float* __restrict__ b_n,
    const float* __restrict__ ig,   // [steps,3,H] fp32 for this chunk
    float* __restrict__ hs,         // [steps,H] output states (chunk base)
    float4* __restrict__ atoms,     // 2 x 1024 atoms, zeroed at launch
    int base, int steps)
{
    __shared__ float h_lds[HID];
    __shared__ float pg[16][3];
    __shared__ float hg_lds[24];
    const int tid  = threadIdx.x;
    const int lane = tid & 63;
    const int w    = tid >> 6;      // wave 0..15
    const int pr   = tid & 127;     // pair-local lane 0..127
    const int k    = tid >> 7;      // wave-pair 0..7
    const int b    = blockIdx.x;

    // ---- 48 weights per thread (12 float4), coalesced ----
    // rows idx3 = 3k+j ; cols 4*pr + 512*m (m=0..3)
    float4 wreg[3][4];
    #pragma unroll
    for (int j = 0; j < 3; j++) {
        const int idx3 = 3 * k + j;
        const float* wp = w_hh +
            (size_t)((idx3 >> 3) * HID + b * 8 + (idx3 & 7)) * HID;
        #pragma unroll
        for (int m = 0; m < 4; m++)
            wreg[j][m] = *(const float4*)(wp + 4 * pr + 512 * m);
    }

    const int i = b * 8 + tid;                 // valid for tid<8
    const float bn = (tid < 8) ? b_n[i] : 0.f;

    for (int t = 0; t < steps; t++) {
        // ig loads for this step (tid<8, wave 0) - in flight during poll
        float ig0 = 0.f, ig1 = 0.f, ig2 = 0.f;
        if (tid < 8) {
            const float* p = ig + (size_t)t * H3 + i;
            ig0 = p[0]; ig1 = p[HID]; ig2 = p[2 * HID];
        }

        // ---- poll own atom: one IC round trip returns stamp AND data ----
        const float target = (float)(base + t);          // exact in fp32
        const float* ap = (const float*)(atoms + (t & 1) * 1024 + tid);
        float4 f;
        do { f = cload_f4(ap); } while (f.z < target);
        *(float2*)&h_lds[2 * tid] = make_float2(f.x, f.y);
        BAR_LDS();

        // ---- dot: rows 3k..3k+2, cols 4*pr+512m, weights in registers ----
        float a0 = 0.f, a1 = 0.f, a2 = 0.f;
        #pragma unroll
        for (int m = 0; m < 4; m++) {
            float4 h4 = *(const float4*)&h_lds[4 * pr + 512 * m];
            a0 += wreg[0][m].x * h4.x + wreg[0][m].y * h4.y + wreg[0][m].z * h4.z + wreg[0][m].w * h4.w;
            a1 += wreg[1][m].x * h4.x + wreg[1][m].y * h4.y + wreg[1][m].z * h4.z + wreg[1][m].w * h4.w;
            a2 += wreg[2][m].x * h4.x + wreg[2][m].y * h4.y + wreg[2][m].z * h4.z + wreg[2][m].w * h4.w;
        }
        #pragma unroll
        for (int s = 32; s >= 1; s >>= 1) {
            a0 += __shfl_xor(a0, s, 64);
            a1 += __shfl_xor(a1, s, 64);
            a2 += __shfl_xor(a2, s, 64);
        }
        if (lane == 0) { pg[w][0] = a0; pg[w][1] = a1; pg[w][2] = a2; }
        BAR_LDS();

        // ---- combine + gates + publish (all in wave 0, lockstep) ----
        if (w == 0) {
            if (lane < 24) {
                const int kk = lane / 3, j = lane - 3 * kk;
                hg_lds[lane] = pg[2 * kk][j] + pg[2 * kk + 1][j];
            }
            asm volatile("s_waitcnt lgkmcnt(0)" ::: "memory");  // intra-wave LDS wr->rd
            float h_new = 0.f;
            if (lane < 8) {
                const float r = fsigmoid(ig0 + hg_lds[lane]);
                const float z = fsigmoid(ig1 + hg_lds[8 + lane]);
                const float n = ftanh_(ig2 + r * (hg_lds[16 + lane] + bn));
                const float hp = h_lds[i];
                h_new = n + z * (hp - n);
            }
            const float ha = __shfl(h_new, lane * 2, 64);
            const float hb = __shfl(h_new, lane * 2 + 1, 64);
            if (lane < 4) {
                cstore_f4(atoms + ((t + 1) & 1) * 1024 + b * 4 + lane,
                          ha, hb, (float)(base + t + 1), 0.f);
            }
            if (lane < 8)
                hs[(size_t)t * HID + i] = h_new;  // cached store, off critical path
        }
        // no end barrier: self-atom gating + top barrier provide ordering
    }
}

// ---------------------------------------------------------------------------
extern "C" void kernel_launch(void* const* d_in, const int* in_sizes, int n_in,
                              void* d_out, int out_size, void* d_ws, size_t ws_size,
                              hipStream_t stream) {
    const float* x     = (const float*)d_in[0];
    const float* enc_w = (const float*)d_in[1];
    const float* enc_b = (const float*)d_in[2];
    const float* w_ih  = (const float*)d_in[3];
    const float* w_hh  = (const float*)d_in[4];
    const float* b_ih  = (const float*)d_in[5];
    const float* b_n   = (const float*)d_in[6];
    const float* w0    = (const float*)d_in[7];
    const float* b0    = (const float*)d_in[8];
    const float* w1    = (const float*)d_in[9];
    const float* b1    = (const float*)d_in[10];
    const float* w2    = (const float*)d_in[11];
    const float* b2    = (const float*)d_in[12];
    float* out = (float*)d_out;

    // workspace (~136 MB): R1 64MB (ig chunk -> dec h1), R2 64MB (hs -> dec h2)
    float* R1    = (float*)d_ws;                          // 16,777,216 f
    float* R2    = R1 + (size_t)16777216;                 // 16,777,216 f
    float* wcomb = R2 + (size_t)16777216;                 // 393,216 f
    float* bcomb = wcomb + 393216;                        // 6,144 f
    float4* atoms = (float4*)(bcomb + 6144);              // 2*1024 float4 = 32KB

    (void)hipMemsetAsync(atoms, 0, 2 * 1024 * sizeof(float4), stream);

    // fold encoder into GRU input weights:
    //   W_comb = w_ih @ enc_w   [6144,64];  b_comb = w_ih @ enc_b + b_ih
    sgemm_nn<<<dim3(1, 96), 256, 0, stream>>>(w_ih, enc_w, wcomb, 6144, 64, 2048);
    bcomb_kernel<<<dim3(1536), 256, 0, stream>>>(w_ih, enc_b, b_ih, bcomb);

    // chunked: ig = x @ W_comb^T + b_comb (K=64), then sequential scan
    for (int c = 0; c < T_STEPS / CHUNK; c++) {
        sgemm_bias<0><<<dim3(H3 / 64, CHUNK / 64), 256, 0, stream>>>(
            x + (size_t)c * CHUNK * 64, wcomb, bcomb, R1, CHUNK, H3, 64);
        gru_scan<<<dim3(NBLK), dim3(1024), 0, stream>>>(
            w_hh, b_n, R1, R2 + (size_t)c * CHUNK * HID, atoms, c * CHUNK, CHUNK);
    }

    // decoder MLP (aliased: R2=hs -> R1=h1 -> R2=h2 -> out)
    sgemm_bias<1><<<dim3(HID / 64, T_STEPS / 64), 256, 0, stream>>>(
        R2, w0, b0, R1, T_STEPS, HID, HID);
    sgemm_bias<1><<<dim3(HID / 64, T_STEPS / 64), 256, 0, stream>>>(
        R1, w1, b1, R2, T_STEPS, HID, HID);
    sgemm_bias<0><<<dim3(1, T_STEPS / 64), 256, 0, stream>>>(
        R2, w2, b2, out, T_STEPS, 49, 2048);
}